// Round 2
// baseline (3518.999 us; speedup 1.0000x reference)
//
#include <hip/hip_runtime.h>

typedef __bf16 bf16_t;
typedef __bf16 bf16x8 __attribute__((ext_vector_type(8)));
typedef float floatx4 __attribute__((ext_vector_type(4)));
typedef _Float16 half2v __attribute__((ext_vector_type(2)));

#define GRU_STEPS 120
#define OUTC 31
#define AST 264          // Abuf row stride (elements); 528B = 33*16 keeps b128 16B-aligned
#define YST 97           // Ybuf row stride (dwords); odd-ish so q-rows land on distinct banks

// ws layout (bytes):
//   blob0 : [0, 524288)          bf16 [8][1024][32]  step-0 weights (x=0)
//   blob1 : [524288, 1048576)    bf16 [8][1024][32]  steady-state weights
//   woutp : [1048576, 1064960)   bf16 [32][256]      W_out padded to 32 rows
//   biasc : [1064960, 1069056)   f32  [1024]         combined gate biases
//   boutp : [1069056, 1069184)   f32  [32]           b_out padded

__global__ void repack_kernel(const float* __restrict__ Wih, const float* __restrict__ Whh,
                              const float* __restrict__ bih, const float* __restrict__ bhh,
                              const float* __restrict__ Wout, const float* __restrict__ bout,
                              bf16_t* __restrict__ blob0, bf16_t* __restrict__ blob1,
                              bf16_t* __restrict__ woutp, float* __restrict__ biasc,
                              float* __restrict__ boutp)
{
    int idx = blockIdx.x * blockDim.x + threadIdx.x;   // 0 .. 1024*256-1
    if (idx >= 1024 * 256) return;
    int n  = idx >> 8;    // blob column (gate output index), 0..1023
    int kk = idx & 255;   // k index, 0..255

    // columns: [0,256) r, [256,512) z (both combined W_ih+W_hh since x==h for t>=1),
    //          [512,768) i_n (W_ih rows 512..767), [768,1024) h_n (W_hh rows 512..767)
    float vih = (n < 768) ? Wih[n * 256 + kk] : 0.f;
    float vhh = (n < 512) ? Whh[n * 256 + kk]
                          : ((n >= 768) ? Whh[(n - 256) * 256 + kk] : 0.f);
    float b1 = (n < 512) ? (vih + vhh) : ((n < 768) ? vih : vhh); // t>=1 (x==h)
    float b0 = (n < 512) ? vhh : ((n < 768) ? 0.f : vhh);         // t==0 (x==0)

    int c = kk >> 5, kloc = kk & 31;
    int off = c * (1024 * 32) + n * 32 + kloc;   // [chunk][n][k] k-contiguous
    blob0[off] = (bf16_t)b0;
    blob1[off] = (bf16_t)b1;

    if (n < 32) woutp[n * 256 + kk] = (bf16_t)((n < OUTC) ? Wout[n * 256 + kk] : 0.f);
    if (idx < 1024) {
        float bb = (idx < 512) ? (bih[idx] + bhh[idx])
                               : ((idx < 768) ? bih[idx] : bhh[idx - 256]);
        biasc[idx] = bb;
    }
    if (idx < 32) boutp[idx] = (idx < OUTC) ? bout[idx] : 0.f;
}

__device__ __forceinline__ float sigmoid_f(float x) {
    return __builtin_amdgcn_rcpf(1.f + __expf(-x));
}
__device__ __forceinline__ float tanh_f(float x) {
    return 1.f - 2.f * __builtin_amdgcn_rcpf(1.f + __expf(2.f * x));
}

// One WG (8 waves, 512 thr) per 64 batch rows; all 120 steps on-chip.
// Per step, two gate phases (p0: r,z ; p1: i_n,h_n) so live accumulators are
// 64 regs not 128, funding a 2-ahead register prefetch ring for B fragments.
__global__ __launch_bounds__(512, 2)
void gru_main(const float* __restrict__ hidden,
              const bf16_t* __restrict__ blob0, const bf16_t* __restrict__ blob1,
              const bf16_t* __restrict__ woutp, const float* __restrict__ biasc,
              const float* __restrict__ boutp, float* __restrict__ out)
{
    __shared__ bf16_t Abuf[64 * AST];     // h tile bf16 [row][k], 33792 B
    __shared__ float  Ybuf[64 * YST];     // y staging, 3 steps x 31 cols, 24832 B

    const int tid = threadIdx.x;
    const int w   = tid >> 6;
    const int l16 = tid & 15;
    const int q   = (tid >> 4) & 3;
    const int rowBase = blockIdx.x * 64;
    const int colBase = w * 32;

    // W_out fragments: registers, loaded once (row = output channel, padded to 32)
    bf16x8 wfr[8];
    {
        const int wrow = (w & 1) * 16 + l16;
#pragma unroll
        for (int c = 0; c < 8; ++c)
            wfr[c] = *reinterpret_cast<const bf16x8*>(woutp + wrow * 256 + c * 32 + q * 8);
    }
    const float ybias = boutp[(w & 1) * 16 + l16];

    float biasv[4][2];
#pragma unroll
    for (int g = 0; g < 4; ++g)
#pragma unroll
        for (int nt = 0; nt < 2; ++nt)
            biasv[g][nt] = biasc[g * 256 + colBase + nt * 16 + l16];

    // fp32 h master, MFMA C-layout: row = mt*16 + q*4 + i, col = colBase + nt*16 + l16
    float h[2][4][4];
#pragma unroll
    for (int nt = 0; nt < 2; ++nt)
#pragma unroll
        for (int mt = 0; mt < 4; ++mt)
#pragma unroll
            for (int i = 0; i < 4; ++i) {
                int row = mt * 16 + q * 4 + i;
                int col = colBase + nt * 16 + l16;
                float v = hidden[(rowBase + row) * 256 + col];
                h[nt][mt][i] = v;
                Abuf[row * AST + col] = (bf16_t)v;
            }
    __syncthreads();

    // B-fragment addressing: group i in [0,16): gp=i>>3 (gate pair), c=i&7 (K chunk);
    // frag j in [0,4): g = gp*2 + (j>>1), nt = j&1.
    const int baseB = (colBase + l16) * 32 + q * 8;
    bf16x8 rb[4][4];   // ring, 2-ahead prefetch

#define LDGROUP(BL, I, SLOT)                                                      \
    {                                                                             \
        _Pragma("unroll")                                                         \
        for (int j = 0; j < 4; ++j) {                                             \
            int g_ = ((I) >> 3) * 2 + (j >> 1), nt_ = j & 1;                      \
            rb[SLOT][j] = *reinterpret_cast<const bf16x8*>(                       \
                (BL) + (size_t)((I) & 7) * 32768 + g_ * 8192 + nt_ * 512 + baseB);\
        }                                                                         \
    }

    LDGROUP(blob0, 0, 0);
    LDGROUP(blob0, 1, 1);

    for (int t = 0; t < GRU_STEPS; ++t) {
        const bf16_t* __restrict__ bl = (t == 0) ? blob0 : blob1;

        half2v rpk[2][4][2], zpk[2][4][2];

#pragma unroll
        for (int gp = 0; gp < 2; ++gp) {
            floatx4 acc[2][2][4];   // [gate-local][nt][mt]
#pragma unroll
            for (int gl = 0; gl < 2; ++gl)
#pragma unroll
                for (int nt = 0; nt < 2; ++nt) {
                    float b = biasv[gp * 2 + gl][nt];
                    floatx4 bi = {b, b, b, b};
#pragma unroll
                    for (int mt = 0; mt < 4; ++mt) acc[gl][nt][mt] = bi;
                }

#pragma unroll
            for (int c = 0; c < 8; ++c) {
                const int i = gp * 8 + c;
                // 2-ahead prefetch; groups 16,17 belong to the next step (blob1)
                if (i + 2 < 16) { LDGROUP(bl, i + 2, (i + 2) & 3); }
                else            { LDGROUP(blob1, i + 2 - 16, (i + 2) & 3); }

                bf16x8 afr[4];
#pragma unroll
                for (int mt = 0; mt < 4; ++mt)
                    afr[mt] = *reinterpret_cast<const bf16x8*>(
                        &Abuf[(mt * 16 + l16) * AST + c * 32 + q * 8]);
#pragma unroll
                for (int j = 0; j < 4; ++j) {
                    const int gl = j >> 1, nt = j & 1;
#pragma unroll
                    for (int mt = 0; mt < 4; ++mt)
                        acc[gl][nt][mt] = __builtin_amdgcn_mfma_f32_16x16x32_bf16(
                            afr[mt], rb[i & 3][j], acc[gl][nt][mt], 0, 0, 0);
                }
            }

            if (gp == 0) {
                // r,z -> sigmoid, park as packed fp16 (range (0,1): fp16-exact enough)
#pragma unroll
                for (int nt = 0; nt < 2; ++nt)
#pragma unroll
                    for (int mt = 0; mt < 4; ++mt)
#pragma unroll
                        for (int p = 0; p < 2; ++p) {
                            half2v rv, zv;
                            rv[0] = (_Float16)sigmoid_f(acc[0][nt][mt][2 * p]);
                            rv[1] = (_Float16)sigmoid_f(acc[0][nt][mt][2 * p + 1]);
                            zv[0] = (_Float16)sigmoid_f(acc[1][nt][mt][2 * p]);
                            zv[1] = (_Float16)sigmoid_f(acc[1][nt][mt][2 * p + 1]);
                            rpk[nt][mt][p] = rv;
                            zpk[nt][mt][p] = zv;
                        }
            } else {
                __syncthreads();   // B1: all Abuf reads of this step done
#pragma unroll
                for (int nt = 0; nt < 2; ++nt)
#pragma unroll
                    for (int mt = 0; mt < 4; ++mt)
#pragma unroll
                        for (int i = 0; i < 4; ++i) {
                            float r = (float)rpk[nt][mt][i >> 1][i & 1];
                            float z = (float)zpk[nt][mt][i >> 1][i & 1];
                            float n = tanh_f(acc[0][nt][mt][i] + r * acc[1][nt][mt][i]);
                            float hv = n + z * (h[nt][mt][i] - n);
                            h[nt][mt][i] = hv;
                            Abuf[(mt * 16 + q * 4 + i) * AST + colBase + nt * 16 + l16] =
                                (bf16_t)hv;
                        }
                __syncthreads();   // B2: new h visible
            }
        }

        // y = h_new @ W_out^T + b_out ; wave w -> tile (mt=w>>1, nt=w&1); into Ybuf
        {
            floatx4 accy = {ybias, ybias, ybias, ybias};
            const int mty = w >> 1, nty = w & 1;
#pragma unroll
            for (int c = 0; c < 8; ++c) {
                bf16x8 a = *reinterpret_cast<const bf16x8*>(
                    &Abuf[(mty * 16 + l16) * AST + c * 32 + q * 8]);
                accy = __builtin_amdgcn_mfma_f32_16x16x32_bf16(a, wfr[c], accy, 0, 0, 0);
            }
            const int ocol = nty * 16 + l16;
            const int slot = (t % 3) * OUTC;
            if (ocol < OUTC) {
#pragma unroll
                for (int i = 0; i < 4; ++i)
                    Ybuf[(mty * 16 + q * 4 + i) * YST + slot + ocol] = accy[i];
            }
        }

        // bulk coalesced flush every 3 steps: 93 contiguous floats per row
        if ((t % 3) == 2) {
            __syncthreads();
            float* obase = out + (size_t)rowBase * (GRU_STEPS * OUTC) + (size_t)(t - 2) * OUTC;
#pragma unroll 1
            for (int i2 = tid; i2 < 64 * 93; i2 += 512) {
                int row = i2 / 93;
                int j   = i2 - row * 93;
                __builtin_nontemporal_store(
                    Ybuf[row * YST + j],
                    obase + (size_t)row * (GRU_STEPS * OUTC) + j);
            }
        }
    }
#undef LDGROUP
}

extern "C" void kernel_launch(void* const* d_in, const int* in_sizes, int n_in,
                              void* d_out, int out_size, void* d_ws, size_t ws_size,
                              hipStream_t stream)
{
    const float* hidden = (const float*)d_in[0];
    const float* Wih    = (const float*)d_in[1];
    const float* Whh    = (const float*)d_in[2];
    const float* bih    = (const float*)d_in[3];
    const float* bhh    = (const float*)d_in[4];
    const float* Wout   = (const float*)d_in[5];
    const float* bout   = (const float*)d_in[6];
    float* out = (float*)d_out;

    char* ws = (char*)d_ws;
    bf16_t* blob0 = (bf16_t*)(ws);
    bf16_t* blob1 = (bf16_t*)(ws + 524288);
    bf16_t* woutp = (bf16_t*)(ws + 1048576);
    float*  biasc = (float*)(ws + 1064960);
    float*  boutp = (float*)(ws + 1069056);

    repack_kernel<<<1024, 256, 0, stream>>>(Wih, Whh, bih, bhh, Wout, bout,
                                            blob0, blob1, woutp, biasc, boutp);
    gru_main<<<256, 512, 0, stream>>>(hidden, blob0, blob1, woutp, biasc, boutp, out);
}